// Round 8
// baseline (215.338 us; speedup 1.0000x reference)
//
#include <hip/hip_runtime.h>
#include <math.h>

#define BB 32
#define NN 8192
#define DD 128
#define KK 64
#define TPB 512
#define CAP 1280   // provable M <= 1024 for distinct keys; headroom for rare ties

__device__ __forceinline__ unsigned monokey(float f) {
    unsigned u = __float_as_uint(f);
    return (u & 0x80000000u) ? ~u : (u | 0x80000000u);   // monotone-unsigned float
}

// ---------------- Kernel 1: fused m1-normalize + cosine -> monotone keys + inv_norm ----
// Block = 64 contiguous row-pairs of one batch (2048 blocks, b = blk>>6).
// Wave owns 16 contiguous pairs; lanes 0-31 row 2p, 32-63 row 2p+1; lane = one float4.
__global__ __launch_bounds__(256) void cos_kernel(const float* __restrict__ modal2,
                                                  const float* __restrict__ modal1,
                                                  unsigned* __restrict__ key_out,
                                                  float* __restrict__ inv_out) {
    const int tid = threadIdx.x;
    const int lane = tid & 63, wid = tid >> 6;
    const int b = blockIdx.x >> 6;

    __shared__ __align__(16) float m1s[DD];
    __shared__ float red[2];

    float x = 0.f;
    if (tid < DD) {
        x = modal1[b * DD + tid];
        float s = x * x;
        #pragma unroll
        for (int off = 32; off > 0; off >>= 1) s += __shfl_xor(s, off);
        if (lane == 0) red[wid] = s;
    }
    __syncthreads();
    if (tid < DD) {
        float s1 = red[0] + red[1];
        float inv1 = 1.0f / fmaxf(sqrtf(s1), 1e-12f);
        float s2 = s1 * inv1 * inv1;
        float inv2 = 1.0f / fmaxf(sqrtf(s2), 1e-8f);
        m1s[tid] = x * (inv1 * inv2);
    }
    __syncthreads();

    const int sub = lane >> 5;
    const int c = lane & 31;
    const float4 mv = *reinterpret_cast<const float4*>(&m1s[c * 4]);
    const int pair0 = blockIdx.x * 64 + wid * 16;

    #pragma unroll 4
    for (int i = 0; i < 16; ++i) {
        int r = (pair0 + i) * 2 + sub;
        const float4 xv = *reinterpret_cast<const float4*>(modal2 + (size_t)r * DD + c * 4);
        float ss = xv.x * xv.x + xv.y * xv.y + xv.z * xv.z + xv.w * xv.w;
        float dd = xv.x * mv.x + xv.y * mv.y + xv.z * mv.z + xv.w * mv.w;
        #pragma unroll
        for (int off = 16; off > 0; off >>= 1) {
            ss += __shfl_xor(ss, off);
            dd += __shfl_xor(dd, off);
        }
        if (c == 0) {
            float inv1 = 1.0f / fmaxf(sqrtf(ss), 1e-12f);   // F.normalize eps
            float s2 = ss * inv1 * inv1;                     // ||m2||^2 after norm
            float inv2 = 1.0f / fmaxf(sqrtf(s2), 1e-8f);     // cosine_similarity renorm
            key_out[r] = monokey(dd * inv1 * inv2);
            inv_out[r] = inv1;
        }
    }
}

// ---------------- Kernel 2: pivot-select top-K + softmax-weighted gather ----------------
// Pivot q = 64th-largest of 512 per-thread maxima (16 keys each, in registers).
// Guarantees: count(keys>=q) in [64, 1024] for distinct keys -> tiny exact-rank set.
__global__ __launch_bounds__(TPB) void topk_kernel(const float* __restrict__ modal2,
                                                   const unsigned* __restrict__ keys_g,
                                                   const float* __restrict__ inv_norm,
                                                   const float* __restrict__ weights,
                                                   float* __restrict__ out) {
    const int b = blockIdx.x;
    const int tid = threadIdx.x;

    __shared__ unsigned tmax_s[TPB];
    __shared__ unsigned long long cand[CAP];
    __shared__ int cnt;
    __shared__ unsigned qs;
    __shared__ int topk_idx[KK];
    __shared__ float coef[KK];
    __shared__ __align__(16) float partial[4][DD];

    // 16 keys/thread in registers (4x uint4, coalesced)
    const uint4* krow = reinterpret_cast<const uint4*>(keys_g + (size_t)b * NN);
    uint4 kv0 = krow[tid], kv1 = krow[tid + TPB], kv2 = krow[tid + 2 * TPB], kv3 = krow[tid + 3 * TPB];
    if (tid == 0) cnt = 0;

    unsigned tmax = 0u;
    #define TM(v) tmax = max(tmax, max(max((v).x, (v).y), max((v).z, (v).w)))
    TM(kv0); TM(kv1); TM(kv2); TM(kv3);
    #undef TM
    tmax_s[tid] = tmax;
    __syncthreads();

    // exact rank of tmax among 512 (ties -> lower tid first); rank 63 is the pivot
    int rnk = 0;
    for (int j = 0; j < TPB; ++j) {
        unsigned o = tmax_s[j];                 // LDS broadcast read
        rnk += (o > tmax) || (o == tmax && j < tid);
    }
    if (rnk == KK - 1) qs = tmax;
    __syncthreads();
    const unsigned q = qs;

    // compact keys >= q  (expected ~80, provably <= 1024 when keys distinct)
    #define EMIT(kx, nx)                                                          \
        if ((kx) >= q) {                                                          \
            int pos = atomicAdd(&cnt, 1);                                         \
            if (pos < CAP)                                                        \
                cand[pos] = ((unsigned long long)(kx) << 32) | (unsigned)(NN - 1 - (nx)); \
        }
    #define EMIT4(v, j)                                   \
        { int n0 = (tid + (j) * TPB) * 4;                 \
          EMIT((v).x, n0); EMIT((v).y, n0 + 1);           \
          EMIT((v).z, n0 + 2); EMIT((v).w, n0 + 3); }
    EMIT4(kv0, 0); EMIT4(kv1, 1); EMIT4(kv2, 2); EMIT4(kv3, 3);
    #undef EMIT4
    #undef EMIT
    __syncthreads();
    const int M = min(cnt, CAP);

    // exact ordered ranks over M candidates; keys unique (index embedded) ->
    // ranks distinct; value-tie -> larger (NN-1-n) first = smaller n, per lax.top_k
    for (int i = tid; i < M; i += TPB) {
        unsigned long long key = cand[i];
        int r = 0;
        for (int j = 0; j < M; ++j) r += (cand[j] > key);
        if (r < KK) topk_idx[r] = NN - 1 - (int)(key & 0xffffffffu);
    }
    __syncthreads();

    // softmax over weights[b,:] on wave 0; coef[k] = w[k] * inv_norm[b, idx[k]]
    if (tid < 64) {
        float wv = weights[b * KK + tid];
        float mx = wv;
        #pragma unroll
        for (int off = 32; off > 0; off >>= 1) mx = fmaxf(mx, __shfl_xor(mx, off));
        float e = expf(wv - mx);
        float s = e;
        #pragma unroll
        for (int off = 32; off > 0; off >>= 1) s += __shfl_xor(s, off);
        coef[tid] = (e / s) * inv_norm[(size_t)b * NN + topk_idx[tid]];
    }
    __syncthreads();

    // out[b,d] = sum_k coef[k] * modal2[b, idx[k], d], 4 k-quarters in parallel
    {
        int d = tid & (DD - 1);
        int qq = tid >> 7;                       // 0..3
        const float* bbase = modal2 + (size_t)b * NN * DD;
        float acc = 0.f;
        #pragma unroll
        for (int k = 0; k < KK / 4; ++k) {
            int kk = qq * (KK / 4) + k;
            acc += coef[kk] * bbase[(size_t)topk_idx[kk] * DD + d];
        }
        partial[qq][d] = acc;
        __syncthreads();
        if (tid < DD)
            out[b * DD + tid] = (partial[0][tid] + partial[1][tid]) +
                                (partial[2][tid] + partial[3][tid]);
    }
}

extern "C" void kernel_launch(void* const* d_in, const int* in_sizes, int n_in,
                              void* d_out, int out_size, void* d_ws, size_t ws_size,
                              hipStream_t stream) {
    const float* modal1  = (const float*)d_in[0];
    const float* modal2  = (const float*)d_in[1];
    const float* weights = (const float*)d_in[2];
    float* out = (float*)d_out;

    char* ws = (char*)d_ws;
    unsigned* keys  = (unsigned*)ws;                      // 32*8192*4 = 1 MB
    float* inv_norm = (float*)(ws + (size_t)BB * NN * 4); // 1 MB

    cos_kernel<<<2048, 256, 0, stream>>>(modal2, modal1, keys, inv_norm);
    topk_kernel<<<BB, TPB, 0, stream>>>(modal2, keys, inv_norm, weights, out);
}

// Round 9
// 207.206 us; speedup vs baseline: 1.0392x; 1.0392x over previous
//
#include <hip/hip_runtime.h>
#include <math.h>

#define BB 32
#define NN 8192
#define DD 128
#define KK 64
#define NBINS 4096
#define CAP 2048

__device__ __forceinline__ unsigned monokey(float f) {
    unsigned u = __float_as_uint(f);
    return (u & 0x80000000u) ? ~u : (u | 0x80000000u);   // monotone-unsigned float
}

// ---------------- Kernel 1: fused m1-normalize + cosine + inv_norm ----------------
// Block = 64 contiguous row-pairs of one batch (2048 blocks total, b = blk>>6).
// Each wave owns 16 contiguous pairs; lanes 0-31 row 2p, 32-63 row 2p+1;
// lane holds one float4 of the row. m1c fragment hoisted to registers.
__global__ __launch_bounds__(256) void cos_kernel(const float* __restrict__ modal2,
                                                  const float* __restrict__ modal1,
                                                  float* __restrict__ cos_out,
                                                  float* __restrict__ inv_out) {
    const int tid = threadIdx.x;
    const int lane = tid & 63, wid = tid >> 6;
    const int b = blockIdx.x >> 6;                 // 64 blocks per batch

    __shared__ __align__(16) float m1s[DD];
    __shared__ float red[2];

    // double-normalized modal1 row -> LDS (threads 0..127; s2 = s1*inv1^2 algebraically)
    float x = 0.f;
    if (tid < DD) {
        x = modal1[b * DD + tid];
        float s = x * x;
        #pragma unroll
        for (int off = 32; off > 0; off >>= 1) s += __shfl_xor(s, off);
        if (lane == 0) red[wid] = s;               // wid 0/1 only
    }
    __syncthreads();
    if (tid < DD) {
        float s1 = red[0] + red[1];
        float inv1 = 1.0f / fmaxf(sqrtf(s1), 1e-12f);
        float s2 = s1 * inv1 * inv1;
        float inv2 = 1.0f / fmaxf(sqrtf(s2), 1e-8f);
        m1s[tid] = x * (inv1 * inv2);
    }
    __syncthreads();

    const int sub = lane >> 5;                     // row within pair
    const int c = lane & 31;                       // float4 slot
    const float4 mv = *reinterpret_cast<const float4*>(&m1s[c * 4]);
    const int pair0 = blockIdx.x * 64 + wid * 16;

    #pragma unroll 4
    for (int i = 0; i < 16; ++i) {
        int r = (pair0 + i) * 2 + sub;
        const float4 xv = *reinterpret_cast<const float4*>(modal2 + (size_t)r * DD + c * 4);
        float ss = xv.x * xv.x + xv.y * xv.y + xv.z * xv.z + xv.w * xv.w;
        float dd = xv.x * mv.x + xv.y * mv.y + xv.z * mv.z + xv.w * mv.w;
        #pragma unroll
        for (int off = 16; off > 0; off >>= 1) {   // within 32-lane group
            ss += __shfl_xor(ss, off);
            dd += __shfl_xor(dd, off);
        }
        if (c == 0) {
            float inv1 = 1.0f / fmaxf(sqrtf(ss), 1e-12f);   // F.normalize eps
            float s2 = ss * inv1 * inv1;                     // ||m2||^2 after norm
            float inv2 = 1.0f / fmaxf(sqrtf(s2), 1e-8f);     // cosine_similarity renorm
            cos_out[r] = dd * inv1 * inv2;
            inv_out[r] = inv1;
        }
    }
}

// ---------------- Kernel 2: histogram-select top-K + softmax-weighted gather ----------------
__global__ __launch_bounds__(256) void topk_kernel(const float* __restrict__ modal2,
                                                   const float* __restrict__ cos_sim,
                                                   const float* __restrict__ inv_norm,
                                                   const float* __restrict__ weights,
                                                   float* __restrict__ out) {
    const int b = blockIdx.x;
    const int tid = threadIdx.x;
    const int lane = tid & 63, wid = tid >> 6;

    __shared__ __align__(16) unsigned keys[NN];          // 32 KB monotone keys
    __shared__ unsigned bins[NBINS];                     // 16 KB
    __shared__ unsigned long long cand[CAP];             // 16 KB
    __shared__ int cnt, thr_sh;
    __shared__ int topk_idx[KK];
    __shared__ float coef[KK];
    __shared__ __align__(16) float partial[DD];

    // zero bins + cnt; load row -> monotone keys (float4/uint4)
    for (int j = tid; j < NBINS; j += 256) bins[j] = 0u;
    if (tid == 0) cnt = 0;
    const float* crow = cos_sim + (size_t)b * NN;
    #pragma unroll
    for (int j = 0; j < NN / 4 / 256; ++j) {
        int i = (tid + j * 256) * 4;
        float4 v = *reinterpret_cast<const float4*>(&crow[i]);
        uint4 kv = make_uint4(monokey(v.x), monokey(v.y), monokey(v.z), monokey(v.w));
        *reinterpret_cast<uint4*>(&keys[i]) = kv;
    }
    __syncthreads();

    // 12-bit histogram via LDS atomics
    #pragma unroll
    for (int j = 0; j < NN / 256; ++j) {
        int n = tid + j * 256;
        atomicAdd(&bins[keys[n] >> 20], 1u);
    }
    __syncthreads();

    // threshold bin: max t with suffix-count(bins >= t) >= KK (wave 0 only)
    if (tid < 64) {
        unsigned csum = 0;
        #pragma unroll
        for (int j = 0; j < NBINS / 64; ++j) csum += bins[tid * (NBINS / 64) + j];
        unsigned T = csum;                                  // suffix-scan chunk sums
        #pragma unroll
        for (int off = 1; off < 64; off <<= 1) {
            unsigned t2 = __shfl_down(T, off);
            if (tid + off < 64) T += t2;
        }
        unsigned long long mk = __ballot(T >= KK);          // prefix of set bits
        int Cs = 63 - __builtin_clzll(mk);
        unsigned above = (Cs < 63) ? __shfl(T, Cs + 1) : 0u;
        unsigned W = bins[Cs * (NBINS / 64) + tid];         // suffix-scan within chunk
        #pragma unroll
        for (int off = 1; off < 64; off <<= 1) {
            unsigned t2 = __shfl_down(W, off);
            if (tid + off < 64) W += t2;
        }
        unsigned long long mk2 = __ballot(above + W >= KK);
        int off2 = 63 - __builtin_clzll(mk2);
        if (tid == 0) thr_sh = Cs * (NBINS / 64) + off2;
    }
    __syncthreads();
    const int thr = thr_sh;

    // compact candidates (bin >= thr): typically ~K + ~30 for continuous data
    #pragma unroll
    for (int j = 0; j < NN / 256; ++j) {
        int n = tid + j * 256;
        unsigned k = keys[n];
        if ((int)(k >> 20) >= thr) {
            int pos = atomicAdd(&cnt, 1);
            if (pos < CAP)
                cand[pos] = ((unsigned long long)k << 32) | (unsigned)(NN - 1 - n);
        }
    }
    __syncthreads();
    const int M = min(cnt, CAP);                            // M >= KK by construction

    // exact ordered ranks: keys unique (index embedded) -> ranks distinct;
    // tie on value -> larger (NN-1-n) first = smaller n first, matching lax.top_k
    for (int i = tid; i < M; i += 256) {
        unsigned long long key = cand[i];
        int r = 0;
        for (int j = 0; j < M; ++j) r += (cand[j] > key);
        if (r < KK) topk_idx[r] = NN - 1 - (int)(key & 0xffffffffu);
    }
    __syncthreads();

    // softmax over weights[b,:] on wave 0; coef[k] = w[k] * inv_norm[b, idx[k]]
    if (wid == 0) {
        float wv = weights[b * KK + lane];
        float mx = wv;
        #pragma unroll
        for (int off = 32; off > 0; off >>= 1) mx = fmaxf(mx, __shfl_xor(mx, off));
        float e = expf(wv - mx);
        float s = e;
        #pragma unroll
        for (int off = 32; off > 0; off >>= 1) s += __shfl_xor(s, off);
        float w = e / s;
        int idx = topk_idx[lane];
        coef[lane] = w * inv_norm[(size_t)b * NN + idx];
    }
    __syncthreads();

    // out[b,d] = sum_k coef[k] * modal2[b, idx[k], d], split over 2 k-halves
    {
        int d = tid & (DD - 1);
        int half = tid >> 7;
        const float* bbase = modal2 + (size_t)b * NN * DD;
        float acc = 0.f;
        #pragma unroll
        for (int k = 0; k < KK / 2; ++k) {
            int kk2 = half * (KK / 2) + k;
            acc += coef[kk2] * bbase[(size_t)topk_idx[kk2] * DD + d];
        }
        if (half == 0) partial[d] = acc;
        __syncthreads();
        if (half == 1) out[b * DD + d] = partial[d] + acc;
    }
}

extern "C" void kernel_launch(void* const* d_in, const int* in_sizes, int n_in,
                              void* d_out, int out_size, void* d_ws, size_t ws_size,
                              hipStream_t stream) {
    const float* modal1  = (const float*)d_in[0];
    const float* modal2  = (const float*)d_in[1];
    const float* weights = (const float*)d_in[2];
    float* out = (float*)d_out;

    char* ws = (char*)d_ws;
    float* cos_sim  = (float*)ws;                        // 32*8192*4 = 1 MB
    float* inv_norm = (float*)(ws + (size_t)BB * NN * 4);

    cos_kernel<<<2048, 256, 0, stream>>>(modal2, modal1, cos_sim, inv_norm);
    topk_kernel<<<BB, 256, 0, stream>>>(modal2, cos_sim, inv_norm, weights, out);
}